// Round 6
// baseline (1751.947 us; speedup 1.0000x reference)
//
#include <hip/hip_runtime.h>
#include <hip/hip_bf16.h>

#define BB 1024
#define TT 512
#define II 128
#define HH 64
#define EE 128
#define CC 100
#define NB 16          // batch rows per block -> 64 blocks
#define AW 264         // A-plane row stride in bf16 (256 cols + 8 pad: bank spread)

typedef __bf16 bf16x8 __attribute__((ext_vector_type(8)));
typedef float  f32x4  __attribute__((ext_vector_type(4)));

__device__ __forceinline__ float sigm(float v) { return 1.f / (1.f + __expf(-v)); }
__device__ __forceinline__ float tanh_f(float v) {
    v = fminf(fmaxf(v, -15.f), 15.f);
    float e = __expf(2.f * v);
    return (e - 1.f) / (e + 1.f);
}
struct bf2 { __bf16 hi, lo; };
__device__ __forceinline__ bf2 bsplit(float v) {
    bf2 r;
    r.hi = (__bf16)v;
    r.lo = (__bf16)(v - (float)r.hi);
    return r;
}

// Persistent fused 2-layer LSTM via MFMA + bf16x3 (hi*hi + lo*hi + hi*lo).
// Rounds 2-3 lesson: compiler homes big per-thread arrays in AGPRs and taxes
// every VALU use with accvgpr_read. MFMA reads AGPRs natively -> tax vanishes.
// A (activations, [16 x K]) in LDS bf16 hi/lo planes:
//   cols 0..127 = x_t, 128..191 = h0, 192..255 = h1. Layer0 K-tiles 0..5
//   (cols 0..191), layer1 K-tiles at cols 128..255.
// Wave w owns N-tiles {w, w+4, w+8, w+12} == gates i,f,g,o for cells
// w*16..w*16+15, so each lane ends with the full (i,f,g,o) quadruple for
// (batch=4*quad+reg, cell=w*16+lane15): in-register cell update, gates never
// touch LDS, c-state lives in registers.
__global__ __launch_bounds__(256, 1)
void lstm2_mfma(const float* __restrict__ x,
                const float* __restrict__ Wih0, const float* __restrict__ Whh0,
                const float* __restrict__ bih0, const float* __restrict__ bhh0,
                const float* __restrict__ Wih1, const float* __restrict__ Whh1,
                const float* __restrict__ bih1, const float* __restrict__ bhh1,
                float* __restrict__ hlast)
{
    __shared__ __bf16 Ahi[NB][AW];
    __shared__ __bf16 Alo[NB][AW];

    const int tid  = threadIdx.x;
    const int w    = tid >> 6;        // wave 0..3
    const int lane = tid & 63;
    const int quad = lane >> 4;
    const int l16  = lane & 15;
    const int b0   = blockIdx.x * NB;
    const int ncol = w * 16 + l16;    // this lane's cell index (0..63)

    // ---- B fragments (weights), persistent in VGPR/AGPR -------------------
    // B[k][n] = W[n][k]; fragment (kt, s): n = s*64 + ncol, k = kt*32+quad*8+j
    bf16x8 B0h[6][4], B0l[6][4];      // layer 0: K = 192 (x:0..127, h0:128..191)
    bf16x8 B1h[4][4], B1l[4][4];      // layer 1: K = 128 (h0, h1)
    #pragma unroll
    for (int kt = 0; kt < 6; ++kt) {
        #pragma unroll
        for (int s = 0; s < 4; ++s) {
            const int n = s * 64 + ncol;
            const float* p = (kt < 4)
                ? Wih0 + (size_t)n * II + kt * 32 + quad * 8
                : Whh0 + (size_t)n * HH + (kt - 4) * 32 + quad * 8;
            float4 u = *(const float4*)p, v = *(const float4*)(p + 4);
            float vv[8] = {u.x, u.y, u.z, u.w, v.x, v.y, v.z, v.w};
            #pragma unroll
            for (int i = 0; i < 8; ++i) {
                bf2 sp = bsplit(vv[i]);
                B0h[kt][s][i] = sp.hi;
                B0l[kt][s][i] = sp.lo;
            }
        }
    }
    #pragma unroll
    for (int kt = 0; kt < 4; ++kt) {
        #pragma unroll
        for (int s = 0; s < 4; ++s) {
            const int n = s * 64 + ncol;
            const float* p = (kt < 2)
                ? Wih1 + (size_t)n * HH + kt * 32 + quad * 8
                : Whh1 + (size_t)n * HH + (kt - 2) * 32 + quad * 8;
            float4 u = *(const float4*)p, v = *(const float4*)(p + 4);
            float vv[8] = {u.x, u.y, u.z, u.w, v.x, v.y, v.z, v.w};
            #pragma unroll
            for (int i = 0; i < 8; ++i) {
                bf2 sp = bsplit(vv[i]);
                B1h[kt][s][i] = sp.hi;
                B1l[kt][s][i] = sp.lo;
            }
        }
    }
    float bv0[4], bv1[4];
    #pragma unroll
    for (int s = 0; s < 4; ++s) {
        bv0[s] = bih0[s * 64 + ncol] + bhh0[s * 64 + ncol];
        bv1[s] = bih1[s * 64 + ncol] + bhh1[s * 64 + ncol];
    }

    // ---- zero h0/h1 planes ------------------------------------------------
    for (int i = tid; i < NB * 128; i += 256) {
        int m = i >> 7, c = 128 + (i & 127);
        Ahi[m][c] = (__bf16)0.f;
        Alo[m][c] = (__bf16)0.f;
    }

    // ---- x staging: thread (xm, xi) handles 8 floats of row xm ------------
    const int xm = tid >> 4;
    const int xi = (tid & 15) * 8;
    const float* xptr = x + ((size_t)(b0 + xm) * TT) * II + xi;
    {   // write x(0)
        float4 u = *(const float4*)xptr, v = *(const float4*)(xptr + 4);
        float vv[8] = {u.x, u.y, u.z, u.w, v.x, v.y, v.z, v.w};
        bf16x8 xh, xl;
        #pragma unroll
        for (int i = 0; i < 8; ++i) {
            bf2 sp = bsplit(vv[i]);
            xh[i] = sp.hi;
            xl[i] = sp.lo;
        }
        *(bf16x8*)&Ahi[xm][xi] = xh;
        *(bf16x8*)&Alo[xm][xi] = xl;
    }
    float4 xa = *(const float4*)(xptr + II);       // prefetch x(1)
    float4 xb = *(const float4*)(xptr + II + 4);

    float c0[4] = {0.f, 0.f, 0.f, 0.f}, c1[4] = {0.f, 0.f, 0.f, 0.f};
    float h1v[4] = {0.f, 0.f, 0.f, 0.f};

    __syncthreads();

    for (int t = 0; t < TT; ++t) {
        // ===== S1: layer-0 MFMA + in-register cell update ==================
        f32x4 acc[4];
        #pragma unroll
        for (int s = 0; s < 4; ++s) acc[s] = (f32x4){bv0[s], bv0[s], bv0[s], bv0[s]};
        {
            bf16x8 ah[6], al[6];
            #pragma unroll
            for (int kt = 0; kt < 6; ++kt) {
                ah[kt] = *(const bf16x8*)&Ahi[l16][kt * 32 + quad * 8];
                al[kt] = *(const bf16x8*)&Alo[l16][kt * 32 + quad * 8];
            }
            #pragma unroll
            for (int kt = 0; kt < 6; ++kt) {
                #pragma unroll
                for (int s = 0; s < 4; ++s) {
                    acc[s] = __builtin_amdgcn_mfma_f32_16x16x32_bf16(ah[kt], B0h[kt][s], acc[s], 0, 0, 0);
                    acc[s] = __builtin_amdgcn_mfma_f32_16x16x32_bf16(al[kt], B0h[kt][s], acc[s], 0, 0, 0);
                    acc[s] = __builtin_amdgcn_mfma_f32_16x16x32_bf16(ah[kt], B0l[kt][s], acc[s], 0, 0, 0);
                }
            }
        }
        float h0v[4];
        #pragma unroll
        for (int r = 0; r < 4; ++r) {
            float gi = sigm(acc[0][r]), gf = sigm(acc[1][r]);
            float gg = tanh_f(acc[2][r]), go = sigm(acc[3][r]);
            c0[r] = gf * c0[r] + gi * gg;
            h0v[r] = go * tanh_f(c0[r]);
        }
        __syncthreads();   // bar1: all L0 A-reads done -> safe to overwrite planes

        // ===== S2: store h0(t), x(t+1); prefetch x(t+2) ====================
        #pragma unroll
        for (int r = 0; r < 4; ++r) {
            int m = quad * 4 + r;
            bf2 sp = bsplit(h0v[r]);
            Ahi[m][128 + ncol] = sp.hi;
            Alo[m][128 + ncol] = sp.lo;
        }
        {
            float vv[8] = {xa.x, xa.y, xa.z, xa.w, xb.x, xb.y, xb.z, xb.w};
            bf16x8 xh, xl;
            #pragma unroll
            for (int i = 0; i < 8; ++i) {
                bf2 sp = bsplit(vv[i]);
                xh[i] = sp.hi;
                xl[i] = sp.lo;
            }
            *(bf16x8*)&Ahi[xm][xi] = xh;
            *(bf16x8*)&Alo[xm][xi] = xl;
            int tn = (t + 2 < TT) ? t + 2 : TT - 1;
            xa = *(const float4*)(xptr + (size_t)tn * II);
            xb = *(const float4*)(xptr + (size_t)tn * II + 4);
        }
        __syncthreads();   // bar2: h0(t) visible -> layer-1 may read

        // ===== S3: layer-1 MFMA + in-register cell update ==================
        #pragma unroll
        for (int s = 0; s < 4; ++s) acc[s] = (f32x4){bv1[s], bv1[s], bv1[s], bv1[s]};
        {
            bf16x8 ah[4], al[4];
            #pragma unroll
            for (int kt = 0; kt < 4; ++kt) {
                ah[kt] = *(const bf16x8*)&Ahi[l16][128 + kt * 32 + quad * 8];
                al[kt] = *(const bf16x8*)&Alo[l16][128 + kt * 32 + quad * 8];
            }
            #pragma unroll
            for (int kt = 0; kt < 4; ++kt) {
                #pragma unroll
                for (int s = 0; s < 4; ++s) {
                    acc[s] = __builtin_amdgcn_mfma_f32_16x16x32_bf16(ah[kt], B1h[kt][s], acc[s], 0, 0, 0);
                    acc[s] = __builtin_amdgcn_mfma_f32_16x16x32_bf16(al[kt], B1h[kt][s], acc[s], 0, 0, 0);
                    acc[s] = __builtin_amdgcn_mfma_f32_16x16x32_bf16(ah[kt], B1l[kt][s], acc[s], 0, 0, 0);
                }
            }
        }
        #pragma unroll
        for (int r = 0; r < 4; ++r) {
            float gi = sigm(acc[0][r]), gf = sigm(acc[1][r]);
            float gg = tanh_f(acc[2][r]), go = sigm(acc[3][r]);
            c1[r] = gf * c1[r] + gi * gg;
            h1v[r] = go * tanh_f(c1[r]);
        }
        __syncthreads();   // bar3: all L1 A-reads done -> safe to write h1

        // ===== S4: store h1(t) (read next step after bar1'+bar2') ==========
        #pragma unroll
        for (int r = 0; r < 4; ++r) {
            int m = quad * 4 + r;
            bf2 sp = bsplit(h1v[r]);
            Ahi[m][192 + ncol] = sp.hi;
            Alo[m][192 + ncol] = sp.lo;
        }
    }

    // final h1 (fp32, from registers) -> hlast
    #pragma unroll
    for (int r = 0; r < 4; ++r)
        hlast[(size_t)(b0 + quad * 4 + r) * HH + ncol] = h1v[r];
}

// MLP head: one block per batch row. relu(hW_p^T+b) -> relu(.W_1^T+b) -> .W_2^T+b
__global__ __launch_bounds__(128, 4)
void head_kernel(const float* __restrict__ hlast,
                 const float* __restrict__ Wp, const float* __restrict__ bp,
                 const float* __restrict__ W1, const float* __restrict__ b1,
                 const float* __restrict__ W2, const float* __restrict__ b2,
                 float* __restrict__ out)
{
    __shared__ float hv[HH];
    __shared__ float emb[EE];
    __shared__ float hid[EE];
    const int b = blockIdx.x;
    const int e = threadIdx.x;   // 0..127
    if (e < HH) hv[e] = hlast[(size_t)b * HH + e];
    __syncthreads();
    float z = bp[e];
    #pragma unroll
    for (int j = 0; j < HH; ++j) z += Wp[e * HH + j] * hv[j];
    emb[e] = fmaxf(z, 0.f);
    __syncthreads();
    z = b1[e];
    #pragma unroll
    for (int j = 0; j < EE; ++j) z += W1[e * EE + j] * emb[j];
    hid[e] = fmaxf(z, 0.f);
    __syncthreads();
    if (e < CC) {
        z = b2[e];
        #pragma unroll
        for (int j = 0; j < EE; ++j) z += W2[e * EE + j] * hid[j];
        out[(size_t)b * CC + e] = z;
    }
}

extern "C" void kernel_launch(void* const* d_in, const int* in_sizes, int n_in,
                              void* d_out, int out_size, void* d_ws, size_t ws_size,
                              hipStream_t stream)
{
    const float* x    = (const float*)d_in[0];
    const float* Wih0 = (const float*)d_in[1];
    const float* Whh0 = (const float*)d_in[2];
    const float* bih0 = (const float*)d_in[3];
    const float* bhh0 = (const float*)d_in[4];
    const float* Wih1 = (const float*)d_in[5];
    const float* Whh1 = (const float*)d_in[6];
    const float* bih1 = (const float*)d_in[7];
    const float* bhh1 = (const float*)d_in[8];
    const float* Wp   = (const float*)d_in[9];
    const float* bp   = (const float*)d_in[10];
    const float* W1   = (const float*)d_in[11];
    const float* b1   = (const float*)d_in[12];
    const float* W2   = (const float*)d_in[13];
    const float* b2   = (const float*)d_in[14];

    float* hlast = (float*)d_ws;           // 1024*64 fp32 = 256 KB
    float* out   = (float*)d_out;          // [1024, 100] fp32

    lstm2_mfma<<<BB / NB, 256, 0, stream>>>(x, Wih0, Whh0, bih0, bhh0,
                                            Wih1, Whh1, bih1, bhh1, hlast);
    head_kernel<<<BB, EE, 0, stream>>>(hlast, Wp, bp, W1, b1, W2, b2, out);
}